// Round 1
// baseline (499.083 us; speedup 1.0000x reference)
//
#include <hip/hip_runtime.h>
#include <math.h>

#define NCLUST 512
#define DPER 32
#define NFEAT 1024
#define NSAMP (NCLUST * DPER)   // 16384
#define ALPHA_C 1.0f
#define EPS_C 1e-8f

// ---------------- Kernel A: means, c2, cluster_classes ----------------
__global__ __launch_bounds__(256) void k_means(const float* __restrict__ inp,
                                               const int* __restrict__ target,
                                               float* __restrict__ means,
                                               float* __restrict__ c2,
                                               int* __restrict__ ccls) {
  const int m = blockIdx.x;       // cluster
  const int t = threadIdx.x;      // 256 threads, 4 floats each
  const float* base = inp + (size_t)m * DPER * NFEAT + t * 4;
  float4 s = make_float4(0.f, 0.f, 0.f, 0.f);
  #pragma unroll 8
  for (int d = 0; d < DPER; ++d) {
    float4 v = *(const float4*)(base + (size_t)d * NFEAT);
    s.x += v.x; s.y += v.y; s.z += v.z; s.w += v.w;
  }
  const float inv = 1.0f / 32.0f;
  s.x *= inv; s.y *= inv; s.z *= inv; s.w *= inv;
  *(float4*)(means + (size_t)m * NFEAT + t * 4) = s;
  float sq = s.x * s.x + s.y * s.y + s.z * s.z + s.w * s.w;
  __shared__ float red[4];
  #pragma unroll
  for (int off = 32; off > 0; off >>= 1) sq += __shfl_down(sq, off);
  if ((t & 63) == 0) red[t >> 6] = sq;
  __syncthreads();
  if (t == 0) {
    c2[m] = red[0] + red[1] + red[2] + red[3];
    ccls[m] = target[m * DPER];
  }
}

// ---------------- Kernel B: r2 per row + intra per row ----------------
__global__ __launch_bounds__(256) void k_rows(const float* __restrict__ inp,
                                              const float* __restrict__ means,
                                              const float* __restrict__ c2,
                                              float* __restrict__ r2,
                                              float* __restrict__ intra) {
  const int row = blockIdx.x * 4 + (threadIdx.x >> 6);  // one wave per row
  const int lane = threadIdx.x & 63;
  const int cl = row >> 5;
  const float4* ip = (const float4*)(inp + (size_t)row * NFEAT);
  const float4* mp = (const float4*)(means + (size_t)cl * NFEAT);
  float rr = 0.f, dd = 0.f;
  #pragma unroll
  for (int j = 0; j < 4; ++j) {
    float4 v = ip[lane + 64 * j];
    float4 mv = mp[lane + 64 * j];
    rr += v.x * v.x + v.y * v.y + v.z * v.z + v.w * v.w;
    dd += v.x * mv.x + v.y * mv.y + v.z * mv.z + v.w * mv.w;
  }
  #pragma unroll
  for (int off = 32; off > 0; off >>= 1) {
    rr += __shfl_down(rr, off);
    dd += __shfl_down(dd, off);
  }
  if (lane == 0) {
    r2[row] = rr;
    intra[row] = rr + c2[cl] - 2.0f * dd;
  }
}

// ---------------- Kernel D: variance -> var_norm ----------------
__global__ __launch_bounds__(256) void k_var(const float* __restrict__ intra,
                                             float* __restrict__ vn) {
  const int t = threadIdx.x;
  float s = 0.f;
  for (int i = t; i < NSAMP; i += 256) s += intra[i];
  __shared__ float red[4];
  #pragma unroll
  for (int off = 32; off > 0; off >>= 1) s += __shfl_down(s, off);
  if ((t & 63) == 0) red[t >> 6] = s;
  __syncthreads();
  if (t == 0) {
    float tot = red[0] + red[1] + red[2] + red[3];
    float var = tot / (float)(NSAMP - 1);
    vn[0] = -1.0f / (2.0f * var * var);
  }
}

// ---------------- Kernel E: fused GEMM + epilogue ----------------
// Block: 256 threads, BM=32 rows x all 512 clusters. Thread tile 4 rows x 16
// clusters (clusters strided by 32 -> conflict-free LDS reads with 17-pad).
__global__ __launch_bounds__(256) void k_main(const float* __restrict__ inp,
                                              const float* __restrict__ means,
                                              const float* __restrict__ c2,
                                              const float* __restrict__ r2,
                                              const float* __restrict__ intra,
                                              const float* __restrict__ vnp,
                                              const int* __restrict__ ccls,
                                              const int* __restrict__ target,
                                              float* __restrict__ losses,
                                              float* __restrict__ preds) {
  __shared__ float As[16][32];        // [kk][row]
  __shared__ float Bs[512][17];       // [cluster][kk], pad 17 -> conflict-free
  __shared__ float c2s[512];
  __shared__ int cls_s[512];
  const int t = threadIdx.x;
  const int row0 = blockIdx.x * 32;
  for (int i = t; i < 512; i += 256) { c2s[i] = c2[i]; cls_s[i] = ccls[i]; }
  const int rg = t >> 5;   // 0..7 -> rows rg*4..rg*4+3
  const int cg = t & 31;   // clusters cg + 32*j
  float acc[4][16];
  #pragma unroll
  for (int i = 0; i < 4; ++i)
    #pragma unroll
    for (int j = 0; j < 16; ++j) acc[i][j] = 0.f;

  for (int k0 = 0; k0 < NFEAT; k0 += 16) {
    __syncthreads();
    if (t < 128) {  // stage A: 32 rows x 16 k
      int r = t >> 2, kq = t & 3;
      float4 v = *(const float4*)(inp + (size_t)(row0 + r) * NFEAT + k0 + kq * 4);
      As[kq * 4 + 0][r] = v.x; As[kq * 4 + 1][r] = v.y;
      As[kq * 4 + 2][r] = v.z; As[kq * 4 + 3][r] = v.w;
    }
    #pragma unroll
    for (int jj = 0; jj < 8; ++jj) {  // stage B: 512 clusters x 16 k
      int idx = jj * 256 + t;
      int c = idx >> 2, kq = idx & 3;
      float4 v = *(const float4*)(means + (size_t)c * NFEAT + k0 + kq * 4);
      Bs[c][kq * 4 + 0] = v.x; Bs[c][kq * 4 + 1] = v.y;
      Bs[c][kq * 4 + 2] = v.z; Bs[c][kq * 4 + 3] = v.w;
    }
    __syncthreads();
    #pragma unroll
    for (int kk = 0; kk < 16; ++kk) {
      float a0 = As[kk][rg * 4 + 0];
      float a1 = As[kk][rg * 4 + 1];
      float a2 = As[kk][rg * 4 + 2];
      float a3 = As[kk][rg * 4 + 3];
      float b[16];
      #pragma unroll
      for (int j = 0; j < 16; ++j) b[j] = Bs[cg + 32 * j][kk];
      #pragma unroll
      for (int j = 0; j < 16; ++j) {
        acc[0][j] = fmaf(a0, b[j], acc[0][j]);
        acc[1][j] = fmaf(a1, b[j], acc[1][j]);
        acc[2][j] = fmaf(a2, b[j], acc[2][j]);
        acc[3][j] = fmaf(a3, b[j], acc[3][j]);
      }
    }
  }

  const float vn = vnp[0];
  #pragma unroll
  for (int i = 0; i < 4; ++i) {
    const int grow = row0 + rg * 4 + i;
    const float r2v = r2[grow];
    const int tg = target[grow];
    float bestv = 3.4e38f;
    int bestc = 1 << 30;
    float den = 0.f;
    #pragma unroll
    for (int j = 0; j < 16; ++j) {
      int c = cg + 32 * j;
      float cost = r2v + c2s[c] - 2.0f * acc[i][j];
      if (cls_s[c] != tg) den += expf(vn * cost);
      if (cost < bestv || (cost == bestv && c < bestc)) { bestv = cost; bestc = c; }
    }
    // reduce across the 32 column-groups (stay within 32-lane halves)
    #pragma unroll
    for (int off = 1; off < 32; off <<= 1) {
      float ov = __shfl_xor(bestv, off);
      int oc = __shfl_xor(bestc, off);
      float od = __shfl_xor(den, off);
      den += od;
      if (ov < bestv || (ov == bestv && oc < bestc)) { bestv = ov; bestc = oc; }
    }
    if (cg == 0) {
      float num = expf(vn * intra[grow] - ALPHA_C);
      float ratio = num / (den + EPS_C) + EPS_C;
      float loss = -logf(ratio);
      losses[grow] = loss > 0.f ? loss : 0.f;
      preds[grow] = (float)bestc;
    }
  }
}

// ---------------- Kernel F: total_loss + acc (deterministic) ----------------
__global__ __launch_bounds__(256) void k_final(const float* __restrict__ losses,
                                               const float* __restrict__ preds,
                                               float* __restrict__ out) {
  const int t = threadIdx.x;
  float s = 0.f, cnt = 0.f;
  for (int i = t; i < NSAMP; i += 256) {
    s += losses[i];
    int p = (int)preds[i];
    cnt += (p == (i >> 5)) ? 1.f : 0.f;
  }
  __shared__ float redS[4], redC[4];
  #pragma unroll
  for (int off = 32; off > 0; off >>= 1) {
    s += __shfl_down(s, off);
    cnt += __shfl_down(cnt, off);
  }
  if ((t & 63) == 0) { redS[t >> 6] = s; redC[t >> 6] = cnt; }
  __syncthreads();
  if (t == 0) {
    out[0] = (redS[0] + redS[1] + redS[2] + redS[3]) / (float)NSAMP;
    out[1 + 2 * NSAMP] = (redC[0] + redC[1] + redC[2] + redC[3]) / (float)NSAMP;
  }
}

extern "C" void kernel_launch(void* const* d_in, const int* in_sizes, int n_in,
                              void* d_out, int out_size, void* d_ws, size_t ws_size,
                              hipStream_t stream) {
  const float* inp = (const float*)d_in[0];
  const int* target = (const int*)d_in[1];
  float* out = (float*)d_out;

  float* ws = (float*)d_ws;
  float* means = ws;                 // 512*1024
  float* c2 = means + NCLUST * NFEAT;  // 512
  float* r2 = c2 + NCLUST;             // 16384
  float* intra = r2 + NSAMP;           // 16384
  float* vn = intra + NSAMP;           // 1
  int* ccls = (int*)(vn + 1);          // 512

  float* losses = out + 1;
  float* preds = out + 1 + NSAMP;

  hipLaunchKernelGGL(k_means, dim3(NCLUST), dim3(256), 0, stream,
                     inp, target, means, c2, ccls);
  hipLaunchKernelGGL(k_rows, dim3(NSAMP / 4), dim3(256), 0, stream,
                     inp, means, c2, r2, intra);
  hipLaunchKernelGGL(k_var, dim3(1), dim3(256), 0, stream, intra, vn);
  hipLaunchKernelGGL(k_main, dim3(NSAMP / 32), dim3(256), 0, stream,
                     inp, means, c2, r2, intra, vn, ccls, target, losses, preds);
  hipLaunchKernelGGL(k_final, dim3(1), dim3(256), 0, stream, losses, preds, out);
}

// Round 2
// 131.873 us; speedup vs baseline: 3.7846x; 3.7846x over previous
//
#include <hip/hip_runtime.h>
#include <math.h>

#define NCLUST 512
#define DPER 32
#define NFEAT 1024
#define NSAMP (NCLUST * DPER)   // 16384
#define ALPHA_C 1.0f
#define EPS_C 1e-8f

#define BM 128
#define BN 256
#define BK 64

typedef __attribute__((ext_vector_type(4))) float f32x4;
typedef __attribute__((ext_vector_type(8))) short bf16x8;

__device__ __forceinline__ ushort f2bf(float f) {
  unsigned int u = __float_as_uint(f);
  u += 0x7FFFu + ((u >> 16) & 1u);
  return (ushort)(u >> 16);
}
__device__ __forceinline__ float bf2f(ushort h) {
  return __uint_as_float(((unsigned int)h) << 16);
}

__device__ __forceinline__ f32x4 mfma16(bf16x8 a, bf16x8 b, f32x4 c) {
  return __builtin_amdgcn_mfma_f32_16x16x32_bf16(a, b, c, 0, 0, 0);
}

// ---------------- Kernel A: means, c2, ccls, split-bf16 B ----------------
__global__ __launch_bounds__(256) void k_means(const float* __restrict__ inp,
                                               const int* __restrict__ target,
                                               float* __restrict__ means,
                                               ushort* __restrict__ Bh,
                                               ushort* __restrict__ Bl,
                                               float* __restrict__ c2,
                                               int* __restrict__ ccls) {
  const int m = blockIdx.x;
  const int t = threadIdx.x;      // 256 threads, 4 floats each
  const float* base = inp + (size_t)m * DPER * NFEAT + t * 4;
  float4 s = make_float4(0.f, 0.f, 0.f, 0.f);
  #pragma unroll 8
  for (int d = 0; d < DPER; ++d) {
    float4 v = *(const float4*)(base + (size_t)d * NFEAT);
    s.x += v.x; s.y += v.y; s.z += v.z; s.w += v.w;
  }
  const float inv = 1.0f / 32.0f;
  s.x *= inv; s.y *= inv; s.z *= inv; s.w *= inv;
  *(float4*)(means + (size_t)m * NFEAT + t * 4) = s;
  // split-bf16 halves of the mean
  float sv[4] = {s.x, s.y, s.z, s.w};
  ushort hb[4], lb[4];
  #pragma unroll
  for (int j = 0; j < 4; ++j) {
    hb[j] = f2bf(sv[j]);
    lb[j] = f2bf(sv[j] - bf2f(hb[j]));
  }
  uint2 hw, lw;
  hw.x = (unsigned)hb[0] | ((unsigned)hb[1] << 16);
  hw.y = (unsigned)hb[2] | ((unsigned)hb[3] << 16);
  lw.x = (unsigned)lb[0] | ((unsigned)lb[1] << 16);
  lw.y = (unsigned)lb[2] | ((unsigned)lb[3] << 16);
  *(uint2*)&Bh[(size_t)m * NFEAT + t * 4] = hw;
  *(uint2*)&Bl[(size_t)m * NFEAT + t * 4] = lw;

  float sq = s.x * s.x + s.y * s.y + s.z * s.z + s.w * s.w;
  __shared__ float red[4];
  #pragma unroll
  for (int off = 32; off > 0; off >>= 1) sq += __shfl_down(sq, off);
  if ((t & 63) == 0) red[t >> 6] = sq;
  __syncthreads();
  if (t == 0) {
    c2[m] = red[0] + red[1] + red[2] + red[3];
    ccls[m] = target[m * DPER];
  }
}

// ---------------- Kernel B: r2 per row + intra per row ----------------
__global__ __launch_bounds__(256) void k_rows(const float* __restrict__ inp,
                                              const float* __restrict__ means,
                                              const float* __restrict__ c2,
                                              float* __restrict__ r2,
                                              float* __restrict__ intra) {
  const int row = blockIdx.x * 4 + (threadIdx.x >> 6);
  const int lane = threadIdx.x & 63;
  const int cl = row >> 5;
  const float4* ip = (const float4*)(inp + (size_t)row * NFEAT);
  const float4* mp = (const float4*)(means + (size_t)cl * NFEAT);
  float rr = 0.f, dd = 0.f;
  #pragma unroll
  for (int j = 0; j < 4; ++j) {
    float4 v = ip[lane + 64 * j];
    float4 mv = mp[lane + 64 * j];
    rr += v.x * v.x + v.y * v.y + v.z * v.z + v.w * v.w;
    dd += v.x * mv.x + v.y * mv.y + v.z * mv.z + v.w * mv.w;
  }
  #pragma unroll
  for (int off = 32; off > 0; off >>= 1) {
    rr += __shfl_down(rr, off);
    dd += __shfl_down(dd, off);
  }
  if (lane == 0) {
    r2[row] = rr;
    intra[row] = rr + c2[cl] - 2.0f * dd;
  }
}

// ---------------- Kernel D: variance -> var_norm ----------------
__global__ __launch_bounds__(256) void k_var(const float* __restrict__ intra,
                                             float* __restrict__ vn) {
  const int t = threadIdx.x;
  float s = 0.f;
  for (int i = t; i < NSAMP; i += 256) s += intra[i];
  __shared__ float red[4];
  #pragma unroll
  for (int off = 32; off > 0; off >>= 1) s += __shfl_down(s, off);
  if ((t & 63) == 0) red[t >> 6] = s;
  __syncthreads();
  if (t == 0) {
    float tot = red[0] + red[1] + red[2] + red[3];
    float var = tot / (float)(NSAMP - 1);
    vn[0] = -1.0f / (2.0f * var * var);
  }
}

// ---------------- Kernel E: split-bf16 MFMA GEMM + fused partial epilogue --
// grid 256: rowblk = bid>>1 (128 rows), colblk = bid&1 (256 cols).
// 512 threads = 8 waves, each wave 16 rows x 256 cols.
// A fp32 from global -> registers -> split bf16. B staged LDS (XOR-swizzled).
__global__ __launch_bounds__(512, 2) void k_gemm(const float* __restrict__ inp,
                                                 const ushort* __restrict__ Bh,
                                                 const ushort* __restrict__ Bl,
                                                 const float* __restrict__ c2,
                                                 const float* __restrict__ r2,
                                                 const float* __restrict__ vnp,
                                                 const int* __restrict__ ccls,
                                                 const int* __restrict__ target,
                                                 float* __restrict__ den_p,
                                                 float* __restrict__ minv_p,
                                                 float* __restrict__ minc_p) {
  __shared__ ushort bsh[2][BN * BK];   // 2 x 32 KiB (hi, lo)
  const int t = threadIdx.x;
  const int w = t >> 6;
  const int l = t & 63;
  const int q = l >> 4;        // k-group-of-8 within fragment
  const int cl15 = l & 15;
  const int rowblk = blockIdx.x >> 1;
  const int colblk = blockIdx.x & 1;
  const int row0 = rowblk * BM;
  const int c0 = colblk * BN;

  // staging assignment: thread -> (cluster sc, k-half shr)
  const int sc = t >> 1;       // 0..255
  const int shr = t & 1;       // 0/1 -> k offset 0/32

  const int arow = row0 + w * 16 + cl15;
  const float* aptr = inp + (size_t)arow * NFEAT;

  f32x4 acc[16];
  #pragma unroll
  for (int ct = 0; ct < 16; ++ct) acc[ct] = (f32x4){0.f, 0.f, 0.f, 0.f};

  const int swzc = cl15 & 7;   // lane-constant XOR for reads

  for (int k0 = 0; k0 < NFEAT; k0 += BK) {
    __syncthreads();
    // ---- stage B tile (256 clusters x 64 k, hi+lo) ----
    #pragma unroll
    for (int h = 0; h < 2; ++h) {
      const ushort* src = (h ? Bl : Bh) + (size_t)(c0 + sc) * NFEAT + k0 + shr * 32;
      #pragma unroll
      for (int kc4 = 0; kc4 < 4; ++kc4) {
        int4 v = *(const int4*)(src + kc4 * 8);
        int chunk = (shr * 4 + kc4) ^ (sc & 7);
        *(int4*)&bsh[h][sc * 64 + chunk * 8] = v;
      }
    }
    // ---- A fragments: global fp32 -> split bf16 in regs ----
    bf16x8 ah[2], al[2];
    #pragma unroll
    for (int kg = 0; kg < 2; ++kg) {
      float4 a0 = *(const float4*)(aptr + k0 + kg * 32 + q * 8);
      float4 a1 = *(const float4*)(aptr + k0 + kg * 32 + q * 8 + 4);
      float v[8] = {a0.x, a0.y, a0.z, a0.w, a1.x, a1.y, a1.z, a1.w};
      #pragma unroll
      for (int i = 0; i < 8; ++i) {
        ushort h = f2bf(v[i]);
        ah[kg][i] = (short)h;
        al[kg][i] = (short)f2bf(v[i] - bf2f(h));
      }
    }
    __syncthreads();
    // ---- MFMA inner loop ----
    #pragma unroll
    for (int ct = 0; ct < 16; ++ct) {
      const int cbase = (ct * 16 + cl15) * 64;
      #pragma unroll
      for (int kg = 0; kg < 2; ++kg) {
        const int chunk = (kg * 4 + q) ^ swzc;
        bf16x8 bh = *(const bf16x8*)&bsh[0][cbase + chunk * 8];
        bf16x8 bl = *(const bf16x8*)&bsh[1][cbase + chunk * 8];
        acc[ct] = mfma16(ah[kg], bh, acc[ct]);
        acc[ct] = mfma16(al[kg], bh, acc[ct]);
        acc[ct] = mfma16(ah[kg], bl, acc[ct]);
      }
    }
  }

  // ---- fused epilogue: cost, partial den / argmin over this col-block ----
  const float vn = vnp[0];
  float r2v[4]; int tg[4];
  #pragma unroll
  for (int r = 0; r < 4; ++r) {
    const int grow = row0 + w * 16 + q * 4 + r;
    r2v[r] = r2[grow];
    tg[r] = target[grow];
  }
  float den[4] = {0.f, 0.f, 0.f, 0.f};
  float bv[4] = {3.4e38f, 3.4e38f, 3.4e38f, 3.4e38f};
  int bc[4] = {1 << 30, 1 << 30, 1 << 30, 1 << 30};
  #pragma unroll
  for (int ct = 0; ct < 16; ++ct) {
    const int c = c0 + ct * 16 + cl15;
    const float c2v = c2[c];
    const int cls = ccls[c];
    #pragma unroll
    for (int r = 0; r < 4; ++r) {
      float cost = r2v[r] + c2v - 2.0f * acc[ct][r];
      if (cls != tg[r]) den[r] += expf(vn * cost);
      if (cost < bv[r]) { bv[r] = cost; bc[r] = c; }
    }
  }
  #pragma unroll
  for (int r = 0; r < 4; ++r) {
    #pragma unroll
    for (int off = 1; off < 16; off <<= 1) {
      float od = __shfl_xor(den[r], off);
      float ov = __shfl_xor(bv[r], off);
      int oc = __shfl_xor(bc[r], off);
      den[r] += od;
      if (ov < bv[r] || (ov == bv[r] && oc < bc[r])) { bv[r] = ov; bc[r] = oc; }
    }
    if (cl15 == 0) {
      const int grow = row0 + w * 16 + q * 4 + r;
      den_p[colblk * NSAMP + grow] = den[r];
      minv_p[colblk * NSAMP + grow] = bv[r];
      minc_p[colblk * NSAMP + grow] = (float)bc[r];
    }
  }
}

// ---------------- Kernel F2: combine partials -> losses, preds ----------------
__global__ __launch_bounds__(256) void k_fin2(const float* __restrict__ den_p,
                                              const float* __restrict__ minv_p,
                                              const float* __restrict__ minc_p,
                                              const float* __restrict__ intra,
                                              const float* __restrict__ vnp,
                                              float* __restrict__ losses,
                                              float* __restrict__ preds) {
  const int row = blockIdx.x * 256 + threadIdx.x;
  const float den = den_p[row] + den_p[NSAMP + row];
  const float v0 = minv_p[row], v1 = minv_p[NSAMP + row];
  const float pc = (v1 < v0) ? minc_p[NSAMP + row] : minc_p[row];
  const float num = expf(vnp[0] * intra[row] - ALPHA_C);
  const float ratio = num / (den + EPS_C) + EPS_C;
  float loss = -logf(ratio);
  losses[row] = loss > 0.f ? loss : 0.f;
  preds[row] = pc;
}

// ---------------- Kernel F: total_loss + acc (deterministic) ----------------
__global__ __launch_bounds__(256) void k_final(const float* __restrict__ losses,
                                               const float* __restrict__ preds,
                                               float* __restrict__ out) {
  const int t = threadIdx.x;
  float s = 0.f, cnt = 0.f;
  for (int i = t; i < NSAMP; i += 256) {
    s += losses[i];
    int p = (int)preds[i];
    cnt += (p == (i >> 5)) ? 1.f : 0.f;
  }
  __shared__ float redS[4], redC[4];
  #pragma unroll
  for (int off = 32; off > 0; off >>= 1) {
    s += __shfl_down(s, off);
    cnt += __shfl_down(cnt, off);
  }
  if ((t & 63) == 0) { redS[t >> 6] = s; redC[t >> 6] = cnt; }
  __syncthreads();
  if (t == 0) {
    out[0] = (redS[0] + redS[1] + redS[2] + redS[3]) / (float)NSAMP;
    out[1 + 2 * NSAMP] = (redC[0] + redC[1] + redC[2] + redC[3]) / (float)NSAMP;
  }
}

extern "C" void kernel_launch(void* const* d_in, const int* in_sizes, int n_in,
                              void* d_out, int out_size, void* d_ws, size_t ws_size,
                              hipStream_t stream) {
  const float* inp = (const float*)d_in[0];
  const int* target = (const int*)d_in[1];
  float* out = (float*)d_out;

  float* ws = (float*)d_ws;
  float* means = ws;                          // 512*1024 f32
  ushort* Bh = (ushort*)(means + NCLUST * NFEAT);      // 512*1024 bf16
  ushort* Bl = Bh + NCLUST * NFEAT;                    // 512*1024 bf16
  float* c2 = (float*)(Bl + NCLUST * NFEAT);           // 512
  float* r2 = c2 + NCLUST;                             // 16384
  float* intra = r2 + NSAMP;                           // 16384
  float* vn = intra + NSAMP;                           // 1
  int* ccls = (int*)(vn + 1);                          // 512
  float* den_p = (float*)(ccls + NCLUST);              // 2*16384
  float* minv_p = den_p + 2 * NSAMP;                   // 2*16384
  float* minc_p = minv_p + 2 * NSAMP;                  // 2*16384

  float* losses = out + 1;
  float* preds = out + 1 + NSAMP;

  hipLaunchKernelGGL(k_means, dim3(NCLUST), dim3(256), 0, stream,
                     inp, target, means, Bh, Bl, c2, ccls);
  hipLaunchKernelGGL(k_rows, dim3(NSAMP / 4), dim3(256), 0, stream,
                     inp, means, c2, r2, intra);
  hipLaunchKernelGGL(k_var, dim3(1), dim3(256), 0, stream, intra, vn);
  hipLaunchKernelGGL(k_gemm, dim3((NSAMP / BM) * 2), dim3(512), 0, stream,
                     inp, Bh, Bl, c2, r2, vn, ccls, target, den_p, minv_p, minc_p);
  hipLaunchKernelGGL(k_fin2, dim3(NSAMP / 256), dim3(256), 0, stream,
                     den_p, minv_p, minc_p, intra, vn, losses, preds);
  hipLaunchKernelGGL(k_final, dim3(1), dim3(256), 0, stream, losses, preds, out);
}